// Round 1
// baseline (3131.484 us; speedup 1.0000x reference)
//
#include <hip/hip_runtime.h>

#define SCALEF  0.37796447300922720f   // 1/sqrt(7)
#define EPSF    1e-10f
#define MAXENT  6.93147180559945286f   // ln(1024)

// ---------------- helpers ----------------
__device__ __forceinline__ float wave_sum(float v) {
#pragma unroll
  for (int off = 32; off > 0; off >>= 1) v += __shfl_xor(v, off);
  return v;
}
__device__ __forceinline__ float wave_max(float v) {
#pragma unroll
  for (int off = 32; off > 0; off >>= 1) v = fmaxf(v, __shfl_xor(v, off));
  return v;
}
__device__ __forceinline__ void fma4(float a, float4 b, float4& c) {
  c.x = fmaf(a, b.x, c.x); c.y = fmaf(a, b.y, c.y);
  c.z = fmaf(a, b.z, c.z); c.w = fmaf(a, b.w, c.w);
}
// P0_ij = (0.5*(exp(s1*scale - a1) + exp(s2*scale - a2)) + EPS)^10
__device__ __forceinline__ float p0val(float s1, float s2, float a1, float a2) {
  float p = 0.5f * (__expf(fmaf(s1, SCALEF, -a1)) + __expf(fmaf(s2, SCALEF, -a2))) + EPSF;
  float p2 = p * p, p4 = p2 * p2, p5 = p4 * p;
  return p5 * p5;
}

// ---------------- kernel 0: QKV projection (d-major layouts) + R/C init ----------------
__global__ __launch_bounds__(256) void qkv_kernel(
    const float* __restrict__ x,
    const float* __restrict__ Wq, const float* __restrict__ bq,
    const float* __restrict__ Wk, const float* __restrict__ bk,
    const float* __restrict__ Wv, const float* __restrict__ bv,
    float* __restrict__ Qt, float* __restrict__ Kt, float* __restrict__ Vt,
    float* __restrict__ R, float* __restrict__ C) {
  int row = blockIdx.x * 256 + threadIdx.x;     // 65536 rows
  int b = row >> 10, i = row & 1023;
  float xv[14];
#pragma unroll
  for (int k = 0; k < 14; k++) xv[k] = x[row * 14 + k];
#pragma unroll
  for (int d = 0; d < 14; d++) {
    float q = bq[d], kk = bk[d], vv = bv[d];
#pragma unroll
    for (int k = 0; k < 14; k++) {
      q  = fmaf(xv[k], Wq[d * 14 + k], q);
      kk = fmaf(xv[k], Wk[d * 14 + k], kk);
      vv = fmaf(xv[k], Wv[d * 14 + k], vv);
    }
    int o = b * 14336 + d * 1024 + i;
    Qt[o] = q; Kt[o] = kk; Vt[o] = vv;
  }
  R[row] = 1.0f;
  C[row] = 1.0f;
}

// ---------------- kernel 1: fused attention + entropy/certainty + softmax stats ----------------
// one wave per query row; K then V staged in a single 56KB LDS buffer (two phases)
__global__ __launch_bounds__(512) void attn_kernel(
    const float* __restrict__ Qt, const float* __restrict__ Kt, const float* __restrict__ Vt,
    const float* __restrict__ cert_in,
    float* __restrict__ A1, float* __restrict__ A2,
    float* __restrict__ attn_o, float* __restrict__ cert_out) {
  __shared__ float4 Sl[3584];                   // 56 KB, holds K then V
  int b = blockIdx.x >> 7;                      // 128 blocks per batch
  int rg = blockIdx.x & 127;                    // 8 rows per block
  int tid = threadIdx.x;
  const float4* Ktb = (const float4*)(Kt + b * 14336);
  const float4* Vtb = (const float4*)(Vt + b * 14336);
  for (int idx = tid; idx < 3584; idx += 512) Sl[idx] = Ktb[idx];
  __syncthreads();

  int wave = tid >> 6, lane = tid & 63;
  int i = rg * 8 + wave;
  int row = b * 1024 + i;
  float q[14];
#pragma unroll
  for (int d = 0; d < 14; d++) q[d] = Qt[b * 14336 + d * 1024 + i];

  float4 e1[4], e2[4];
  float m1 = -1e30f, m2 = -1e30f;
#pragma unroll
  for (int t = 0; t < 4; t++) {
    int g = t * 64 + lane;
    float4 s1 = {0, 0, 0, 0}, s2 = {0, 0, 0, 0};
#pragma unroll
    for (int d = 0; d < 7; d++)  fma4(q[d], Sl[d * 256 + g], s1);
#pragma unroll
    for (int d = 7; d < 14; d++) fma4(q[d], Sl[d * 256 + g], s2);
    s1.x *= SCALEF; s1.y *= SCALEF; s1.z *= SCALEF; s1.w *= SCALEF;
    s2.x *= SCALEF; s2.y *= SCALEF; s2.z *= SCALEF; s2.w *= SCALEF;
    e1[t] = s1; e2[t] = s2;
    m1 = fmaxf(m1, fmaxf(fmaxf(s1.x, s1.y), fmaxf(s1.z, s1.w)));
    m2 = fmaxf(m2, fmaxf(fmaxf(s2.x, s2.y), fmaxf(s2.z, s2.w)));
  }
  m1 = wave_max(m1); m2 = wave_max(m2);
  float l1 = 0.f, l2 = 0.f;
#pragma unroll
  for (int t = 0; t < 4; t++) {
    e1[t].x = __expf(e1[t].x - m1); e1[t].y = __expf(e1[t].y - m1);
    e1[t].z = __expf(e1[t].z - m1); e1[t].w = __expf(e1[t].w - m1);
    e2[t].x = __expf(e2[t].x - m2); e2[t].y = __expf(e2[t].y - m2);
    e2[t].z = __expf(e2[t].z - m2); e2[t].w = __expf(e2[t].w - m2);
    l1 += e1[t].x + e1[t].y + e1[t].z + e1[t].w;
    l2 += e2[t].x + e2[t].y + e2[t].z + e2[t].w;
  }
  l1 = wave_sum(l1); l2 = wave_sum(l2);
  float inv1 = 1.0f / l1, inv2 = 1.0f / l2;

  // phase 2: swap V into LDS
  __syncthreads();
  for (int idx = tid; idx < 3584; idx += 512) Sl[idx] = Vtb[idx];
  __syncthreads();

  float acc[14];
#pragma unroll
  for (int d = 0; d < 14; d++) acc[d] = 0.f;
  float ent = 0.f;
#pragma unroll
  for (int t = 0; t < 4; t++) {
    int g = t * 64 + lane;
    float4 p1 = e1[t], p2 = e2[t];
#pragma unroll
    for (int d = 0; d < 7; d++) {
      float4 vv = Sl[d * 256 + g];
      acc[d] += p1.x * vv.x + p1.y * vv.y + p1.z * vv.z + p1.w * vv.w;
    }
#pragma unroll
    for (int d = 7; d < 14; d++) {
      float4 vv = Sl[d * 256 + g];
      acc[d] += p2.x * vv.x + p2.y * vv.y + p2.z * vv.z + p2.w * vv.w;
    }
    float a;
    a = 0.5f * (p1.x * inv1 + p2.x * inv2); ent -= a * __logf(a + EPSF);
    a = 0.5f * (p1.y * inv1 + p2.y * inv2); ent -= a * __logf(a + EPSF);
    a = 0.5f * (p1.z * inv1 + p2.z * inv2); ent -= a * __logf(a + EPSF);
    a = 0.5f * (p1.w * inv1 + p2.w * inv2); ent -= a * __logf(a + EPSF);
  }
  ent = wave_sum(ent);
#pragma unroll
  for (int d = 0; d < 14; d++) acc[d] = wave_sum(acc[d]);

  if (lane == 0) {
    A1[row] = m1 + __logf(l1);
    A2[row] = m2 + __logf(l2);
#pragma unroll
    for (int d = 0; d < 14; d++)
      attn_o[row * 14 + d] = acc[d] * (d < 7 ? inv1 : inv2);
    float sg = 1.0f / (1.0f + __expf(ent - MAXENT));   // sigmoid(MAXENT - ent)
    cert_out[row] = fmaxf(cert_in[row], sg);
  }
}

// ---------------- kernel 2: output projection ----------------
__global__ __launch_bounds__(256) void proj_kernel(
    const float* __restrict__ attn_o, const float* __restrict__ Wo,
    const float* __restrict__ bo, float* __restrict__ out) {
  int idx = blockIdx.x * 256 + threadIdx.x;     // 917504 = 65536*14
  if (idx >= 917504) return;
  int row = idx / 14, d = idx - row * 14;
  float s = bo[d];
  const float* ar = attn_o + row * 14;
  const float* wr = Wo + d * 14;
#pragma unroll
  for (int k = 0; k < 14; k++) s = fmaf(ar[k], wr[k], s);
  out[idx] = s;
}

// ---------------- Sinkhorn pass A: u = P0 @ C, update R ----------------
// block = 512 threads = 8 waves x 4 rows = 32 rows; K staged in LDS
__global__ __launch_bounds__(512) void sinkA_kernel(
    const float* __restrict__ Qt, const float* __restrict__ Kt,
    const float* __restrict__ A1, const float* __restrict__ A2,
    const float* __restrict__ C, float* __restrict__ R) {
  __shared__ float4 Kl[3584];
  int b = blockIdx.x >> 5, blk = blockIdx.x & 31;
  int tid = threadIdx.x;
  const float4* Ktb = (const float4*)(Kt + b * 14336);
  for (int idx = tid; idx < 3584; idx += 512) Kl[idx] = Ktb[idx];
  __syncthreads();

  int wave = tid >> 6, lane = tid & 63;
  int i0 = blk * 32 + wave * 4;
  float q[4][14], a1[4], a2[4], u[4];
#pragma unroll
  for (int rr = 0; rr < 4; rr++) {
#pragma unroll
    for (int d = 0; d < 14; d++) q[rr][d] = Qt[b * 14336 + d * 1024 + i0 + rr];
    a1[rr] = A1[b * 1024 + i0 + rr];
    a2[rr] = A2[b * 1024 + i0 + rr];
    u[rr] = 0.f;
  }
  const float4* Cb = (const float4*)(C + b * 1024);
#pragma unroll
  for (int t = 0; t < 4; t++) {
    int g = t * 64 + lane;
    float4 kv[14];
#pragma unroll
    for (int d = 0; d < 14; d++) kv[d] = Kl[d * 256 + g];
    float4 cv = Cb[g];
#pragma unroll
    for (int rr = 0; rr < 4; rr++) {
      float4 s1 = {0, 0, 0, 0}, s2 = {0, 0, 0, 0};
#pragma unroll
      for (int d = 0; d < 7; d++)  fma4(q[rr][d], kv[d], s1);
#pragma unroll
      for (int d = 7; d < 14; d++) fma4(q[rr][d], kv[d], s2);
      u[rr] += p0val(s1.x, s2.x, a1[rr], a2[rr]) * cv.x;
      u[rr] += p0val(s1.y, s2.y, a1[rr], a2[rr]) * cv.y;
      u[rr] += p0val(s1.z, s2.z, a1[rr], a2[rr]) * cv.z;
      u[rr] += p0val(s1.w, s2.w, a1[rr], a2[rr]) * cv.w;
    }
  }
#pragma unroll
  for (int rr = 0; rr < 4; rr++) u[rr] = wave_sum(u[rr]);
  if (lane == 0) {
#pragma unroll
    for (int rr = 0; rr < 4; rr++) {
      int o = b * 1024 + i0 + rr;
      float rv = R[o];
      rv = rv / fmaf(rv, u[rr], EPSF);
      R[o] = fminf(rv, 1e37f);
    }
  }
}

// ---------------- Sinkhorn pass B: v = P0^T @ R, update C ----------------
__global__ __launch_bounds__(512) void sinkB_kernel(
    const float* __restrict__ Qt, const float* __restrict__ Kt,
    const float* __restrict__ A1, const float* __restrict__ A2,
    const float* __restrict__ R, float* __restrict__ C) {
  __shared__ float4 Ql[3584];
  int b = blockIdx.x >> 5, blk = blockIdx.x & 31;
  int tid = threadIdx.x;
  const float4* Qtb = (const float4*)(Qt + b * 14336);
  for (int idx = tid; idx < 3584; idx += 512) Ql[idx] = Qtb[idx];
  __syncthreads();

  int wave = tid >> 6, lane = tid & 63;
  int j0 = blk * 32 + wave * 4;
  float kk[4][14], v[4];
#pragma unroll
  for (int rr = 0; rr < 4; rr++) {
#pragma unroll
    for (int d = 0; d < 14; d++) kk[rr][d] = Kt[b * 14336 + d * 1024 + j0 + rr];
    v[rr] = 0.f;
  }
  const float4* A1b = (const float4*)(A1 + b * 1024);
  const float4* A2b = (const float4*)(A2 + b * 1024);
  const float4* Rb  = (const float4*)(R + b * 1024);
#pragma unroll
  for (int t = 0; t < 4; t++) {
    int g = t * 64 + lane;
    float4 qv[14];
#pragma unroll
    for (int d = 0; d < 14; d++) qv[d] = Ql[d * 256 + g];
    float4 a1v = A1b[g], a2v = A2b[g], rv = Rb[g];
#pragma unroll
    for (int rr = 0; rr < 4; rr++) {
      float4 s1 = {0, 0, 0, 0}, s2 = {0, 0, 0, 0};
#pragma unroll
      for (int d = 0; d < 7; d++)  fma4(kk[rr][d], qv[d], s1);
#pragma unroll
      for (int d = 7; d < 14; d++) fma4(kk[rr][d], qv[d], s2);
      v[rr] += p0val(s1.x, s2.x, a1v.x, a2v.x) * rv.x;
      v[rr] += p0val(s1.y, s2.y, a1v.y, a2v.y) * rv.y;
      v[rr] += p0val(s1.z, s2.z, a1v.z, a2v.z) * rv.z;
      v[rr] += p0val(s1.w, s2.w, a1v.w, a2v.w) * rv.w;
    }
  }
#pragma unroll
  for (int rr = 0; rr < 4; rr++) v[rr] = wave_sum(v[rr]);
  if (lane == 0) {
#pragma unroll
    for (int rr = 0; rr < 4; rr++) {
      int o = b * 1024 + j0 + rr;
      float cv = C[o];
      cv = cv / fmaf(cv, v[rr], EPSF);
      C[o] = fminf(cv, 1e37f);
    }
  }
}

// ---------------- final argmax over P0_ij * C_j + permutation gather ----------------
__global__ __launch_bounds__(512) void argmax_kernel(
    const float* __restrict__ Qt, const float* __restrict__ Kt,
    const float* __restrict__ A1, const float* __restrict__ A2,
    const float* __restrict__ C, const int* __restrict__ perm,
    float* __restrict__ perm_out) {
  __shared__ float4 Kl[3584];
  int b = blockIdx.x >> 7, rg = blockIdx.x & 127;
  int tid = threadIdx.x;
  const float4* Ktb = (const float4*)(Kt + b * 14336);
  for (int idx = tid; idx < 3584; idx += 512) Kl[idx] = Ktb[idx];
  __syncthreads();

  int wave = tid >> 6, lane = tid & 63;
  int i = rg * 8 + wave;
  int row = b * 1024 + i;
  float q[14];
#pragma unroll
  for (int d = 0; d < 14; d++) q[d] = Qt[b * 14336 + d * 1024 + i];
  float a1 = A1[row], a2 = A2[row];
  const float4* Cb = (const float4*)(C + b * 1024);

  float best = -1.0f;
  int bj = 0;
#pragma unroll
  for (int t = 0; t < 4; t++) {
    int g = t * 64 + lane;
    float4 kv[14];
#pragma unroll
    for (int d = 0; d < 14; d++) kv[d] = Kl[d * 256 + g];
    float4 cv = Cb[g];
    float4 s1 = {0, 0, 0, 0}, s2 = {0, 0, 0, 0};
#pragma unroll
    for (int d = 0; d < 7; d++)  fma4(q[d], kv[d], s1);
#pragma unroll
    for (int d = 7; d < 14; d++) fma4(q[d], kv[d], s2);
    float val;
    val = p0val(s1.x, s2.x, a1, a2) * cv.x; if (val > best) { best = val; bj = 4 * g + 0; }
    val = p0val(s1.y, s2.y, a1, a2) * cv.y; if (val > best) { best = val; bj = 4 * g + 1; }
    val = p0val(s1.z, s2.z, a1, a2) * cv.z; if (val > best) { best = val; bj = 4 * g + 2; }
    val = p0val(s1.w, s2.w, a1, a2) * cv.w; if (val > best) { best = val; bj = 4 * g + 3; }
  }
  // cross-lane argmax, first-index tie-break
#pragma unroll
  for (int off = 32; off > 0; off >>= 1) {
    float ob = __shfl_xor(best, off);
    int oj = __shfl_xor(bj, off);
    if (ob > best || (ob == best && oj < bj)) { best = ob; bj = oj; }
  }
  if (lane == 0) perm_out[row] = (float)perm[b * 1024 + bj];
}

// ---------------- launch ----------------
extern "C" void kernel_launch(void* const* d_in, const int* in_sizes, int n_in,
                              void* d_out, int out_size, void* d_ws, size_t ws_size,
                              hipStream_t stream) {
  const float* x    = (const float*)d_in[0];
  const float* cert = (const float*)d_in[1];
  const int*   perm = (const int*)d_in[2];
  const float* Wq = (const float*)d_in[3];
  const float* bq = (const float*)d_in[4];
  const float* Wk = (const float*)d_in[5];
  const float* bk = (const float*)d_in[6];
  const float* Wv = (const float*)d_in[7];
  const float* bv = (const float*)d_in[8];
  const float* Wo = (const float*)d_in[9];
  const float* bo = (const float*)d_in[10];

  float* out      = (float*)d_out;            // 917504
  float* cert_out = out + 917504;             // 65536
  float* perm_out = out + 983040;             // 65536

  float* ws = (float*)d_ws;
  float* Qt = ws;                    // 917504
  float* Kt = Qt + 917504;           // 917504
  float* Vt = Kt + 917504;           // 917504
  float* A1 = Vt + 917504;           // 65536
  float* A2 = A1 + 65536;            // 65536
  float* R  = A2 + 65536;            // 65536
  float* C  = R + 65536;             // 65536
  float* attn_o = C + 65536;         // 917504  (total ~15.7 MB)

  qkv_kernel<<<256, 256, 0, stream>>>(x, Wq, bq, Wk, bk, Wv, bv, Qt, Kt, Vt, R, C);
  attn_kernel<<<8192, 512, 0, stream>>>(Qt, Kt, Vt, cert, A1, A2, attn_o, cert_out);
  proj_kernel<<<3584, 256, 0, stream>>>(attn_o, Wo, bo, out);
  for (int it = 0; it < 20; it++) {
    sinkA_kernel<<<2048, 512, 0, stream>>>(Qt, Kt, A1, A2, C, R);
    sinkB_kernel<<<2048, 512, 0, stream>>>(Qt, Kt, A1, A2, R, C);
  }
  argmax_kernel<<<8192, 512, 0, stream>>>(Qt, Kt, A1, A2, C, perm, perm_out);
}